// Round 1
// baseline (262.549 us; speedup 1.0000x reference)
//
#include <hip/hip_runtime.h>

// Problem constants (match reference)
#define TB 8
#define TT 400
#define TS 40
#define TV 512
#define SU (TS + 1)          // 41
#define NROWS (TB * TT * SU) // 131200

__global__ __launch_bounds__(256) void rowlse_kernel(
    const float* __restrict__ acts, const int* __restrict__ labels,
    float* __restrict__ lp_blank, float* __restrict__ lp_label)
{
    const int wave = threadIdx.x >> 6;
    const int lane = threadIdx.x & 63;
    const int row  = blockIdx.x * 4 + wave;   // grid*4 == NROWS exactly

    const float* rp = acts + (size_t)row * TV;
    // lane i covers elements [8i, 8i+8)
    float4 a = *(const float4*)(rp + lane * 8);
    float4 b = *(const float4*)(rp + lane * 8 + 4);

    float m = fmaxf(fmaxf(fmaxf(a.x, a.y), fmaxf(a.z, a.w)),
                    fmaxf(fmaxf(b.x, b.y), fmaxf(b.z, b.w)));
#pragma unroll
    for (int off = 1; off < 64; off <<= 1) m = fmaxf(m, __shfl_xor(m, off));

    float s = __expf(a.x - m) + __expf(a.y - m) + __expf(a.z - m) + __expf(a.w - m)
            + __expf(b.x - m) + __expf(b.y - m) + __expf(b.z - m) + __expf(b.w - m);
#pragma unroll
    for (int off = 1; off < 64; off <<= 1) s += __shfl_xor(s, off);

    const float logZ = m + logf(s);

    if (lane == 0) {
        const int u  = row % SU;
        const int bt = row / SU;
        // blank column 0 is lane 0's a.x
        lp_blank[row] = a.x - logZ;
        if (u < TS) {
            const int b_idx = bt / TT;
            const int col   = labels[b_idx * TS + u];
            lp_label[bt * TS + u] = rp[col] - logZ;   // L1-hot reload
        }
    }
}

__global__ __launch_bounds__(64) void alpha_kernel(
    const float* __restrict__ lp_blank, const float* __restrict__ lp_label,
    const int* __restrict__ input_lengths, const int* __restrict__ label_lengths,
    float* __restrict__ out)
{
    const int b = blockIdx.x;
    const int u = threadIdx.x;          // one wave: u in [0,64)

    const int inlen  = input_lengths[b];
    const int lablen = label_lengths[b];

    const float* lpb_base = lp_blank + (size_t)b * TT * SU;
    const float* lpl_base = lp_label + (size_t)b * TT * TS;

    float alpha = (u == 0) ? 0.0f : -1.0e30f;
    float saved = -1.0e30f;

    for (int t = 0; t < TT; ++t) {
        const float lpb = (u <= TS) ? lpb_base[t * SU + u] : -1.0e30f;
        const float lpl = (u >= 1 && u <= TS) ? lpl_base[t * TS + (u - 1)] : 0.0f;

        const float stay = alpha + lpb;
        const float prev = __shfl_up(alpha, 1);

        float nv;
        if (u == 0 || u > TS) {
            nv = stay;
        } else {
            const float move = prev + lpl;
            const float mx = fmaxf(stay, move);
            const float mn = fminf(stay, move);
            nv = mx + log1pf(__expf(mn - mx));
        }
        alpha = nv;
        if (t == inlen - 1) saved = alpha;
    }

    const float cost_alpha = __shfl(saved, lablen);
    if (u == 0) out[b] = -cost_alpha;
}

extern "C" void kernel_launch(void* const* d_in, const int* in_sizes, int n_in,
                              void* d_out, int out_size, void* d_ws, size_t ws_size,
                              hipStream_t stream) {
    const float* acts          = (const float*)d_in[0];
    const int*   labels        = (const int*)d_in[1];
    const int*   input_lengths = (const int*)d_in[2];
    const int*   label_lengths = (const int*)d_in[3];
    float* out = (float*)d_out;

    float* lp_blank = (float*)d_ws;                 // NROWS floats
    float* lp_label = lp_blank + NROWS;             // TB*TT*TS floats

    rowlse_kernel<<<NROWS / 4, 256, 0, stream>>>(acts, labels, lp_blank, lp_label);
    alpha_kernel<<<TB, 64, 0, stream>>>(lp_blank, lp_label,
                                        input_lengths, label_lengths, out);
}

// Round 2
// 66.505 us; speedup vs baseline: 3.9478x; 3.9478x over previous
//
#include <hip/hip_runtime.h>

// Problem constants (match reference)
#define TB 8
#define TT 400
#define TS 40
#define TV 512
#define SU (TS + 1)          // 41
#define NROWS (TB * TT * SU) // 131200
#define KCH 16               // t-steps per register chunk
#define NCH (TT / KCH)       // 25 chunks
#define NEG_INF (-1.0e30f)
#define INV_LN2 1.44269504088896341f
#define LN2 0.69314718055994531f

__global__ __launch_bounds__(256) void rowlse_kernel(
    const float* __restrict__ acts, const int* __restrict__ labels,
    float* __restrict__ lp_blank, float* __restrict__ lp_label)
{
    const int wave = threadIdx.x >> 6;
    const int lane = threadIdx.x & 63;
    const int row  = blockIdx.x * 4 + wave;   // grid*4 == NROWS exactly

    const float* rp = acts + (size_t)row * TV;
    // lane i covers elements [8i, 8i+8)
    float4 a = *(const float4*)(rp + lane * 8);
    float4 b = *(const float4*)(rp + lane * 8 + 4);

    float m = fmaxf(fmaxf(fmaxf(a.x, a.y), fmaxf(a.z, a.w)),
                    fmaxf(fmaxf(b.x, b.y), fmaxf(b.z, b.w)));
#pragma unroll
    for (int off = 1; off < 64; off <<= 1) m = fmaxf(m, __shfl_xor(m, off));

    float s = __expf(a.x - m) + __expf(a.y - m) + __expf(a.z - m) + __expf(a.w - m)
            + __expf(b.x - m) + __expf(b.y - m) + __expf(b.z - m) + __expf(b.w - m);
#pragma unroll
    for (int off = 1; off < 64; off <<= 1) s += __shfl_xor(s, off);

    const float logZ = m + logf(s);

    if (lane == 0) {
        const int u  = row % SU;
        const int bt = row / SU;
        // store in log2 domain (recursion runs base-2: v_exp/v_log are native base-2)
        lp_blank[row] = (a.x - logZ) * INV_LN2;
        if (u < TS) {
            const int b_idx = bt / TT;
            const int col   = labels[b_idx * TS + u];
            lp_label[bt * TS + u] = (rp[col] - logZ) * INV_LN2;   // L1-hot reload
        }
    }
}

// One wave per batch. Lane u holds alpha[u] (log2 domain). t-loop is software-
// pipelined: 16-step chunks double-buffered in registers (A/B, outer loop
// unrolled x2 so all buffer indices are compile-time constants).
__global__ __launch_bounds__(64) void alpha_kernel(
    const float* __restrict__ lp_blank, const float* __restrict__ lp_label,
    const int* __restrict__ input_lengths, const int* __restrict__ label_lengths,
    float* __restrict__ out)
{
    const int b = blockIdx.x;
    const int u = threadIdx.x;          // one wave: u in [0,64)

    const int inlen  = input_lengths[b];
    const int lablen = label_lengths[b];

    // clamped addresses so dead lanes (u>TS) read valid memory; their values
    // are never consumed (shfl only flows upward, lane41+ feeds nothing <=40)
    const int uu = (u <= TS) ? u : TS;
    const int ul = (u >= 1 && u <= TS) ? (u - 1) : 0;
    const float* pb_ptr = lp_blank + (size_t)b * TT * SU + uu;
    const float* pl_ptr = lp_label + (size_t)b * TT * TS + ul;
    const bool u_dead = (u == 0 || u > TS);   // lanes where 'move' is invalid

    float alpha = (u == 0) ? 0.0f : NEG_INF;
    float saved = NEG_INF;

    float pbA[KCH], plA[KCH], pbB[KCH], plB[KCH];

#define LOADC(PB, PL, C) { \
    _Pragma("unroll") \
    for (int k = 0; k < KCH; ++k) { \
        (PB)[k] = pb_ptr[((C) * KCH + k) * SU]; \
        (PL)[k] = pl_ptr[((C) * KCH + k) * TS]; \
    } }

#define COMPUTE(PB, PL, C) { \
    _Pragma("unroll") \
    for (int k = 0; k < KCH; ++k) { \
        const float prev = __shfl_up(alpha, 1); \
        const float stay = alpha + (PB)[k]; \
        const float move = prev + (PL)[k]; \
        const float mx = fmaxf(stay, move); \
        const float mn = fminf(stay, move); \
        float nv = mx + __builtin_amdgcn_logf(1.0f + __builtin_amdgcn_exp2f(mn - mx)); \
        nv = u_dead ? stay : nv; \
        alpha = nv; \
        saved = ((C) * KCH + k == inlen - 1) ? alpha : saved; \
    } }

    LOADC(pbA, plA, 0);
    // 12 double-iterations cover chunks 0..23 and load up to chunk 24
    for (int i = 0; i < 12; ++i) {
        const int c0 = 2 * i;
        LOADC(pbB, plB, c0 + 1);
        COMPUTE(pbA, plA, c0);
        LOADC(pbA, plA, c0 + 2);
        COMPUTE(pbB, plB, c0 + 1);
    }
    COMPUTE(pbA, plA, NCH - 1);   // chunk 24

#undef LOADC
#undef COMPUTE

    const float cost_alpha = __shfl(saved, lablen);
    if (u == 0) out[b] = -cost_alpha * LN2;   // back to natural log
}

extern "C" void kernel_launch(void* const* d_in, const int* in_sizes, int n_in,
                              void* d_out, int out_size, void* d_ws, size_t ws_size,
                              hipStream_t stream) {
    const float* acts          = (const float*)d_in[0];
    const int*   labels        = (const int*)d_in[1];
    const int*   input_lengths = (const int*)d_in[2];
    const int*   label_lengths = (const int*)d_in[3];
    float* out = (float*)d_out;

    float* lp_blank = (float*)d_ws;                 // NROWS floats
    float* lp_label = lp_blank + NROWS;             // TB*TT*TS floats

    rowlse_kernel<<<NROWS / 4, 256, 0, stream>>>(acts, labels, lp_blank, lp_label);
    alpha_kernel<<<TB, 64, 0, stream>>>(lp_blank, lp_label,
                                        input_lengths, label_lengths, out);
}

// Round 3
// 59.134 us; speedup vs baseline: 4.4399x; 1.1247x over previous
//
#include <hip/hip_runtime.h>

// Problem constants (match reference)
#define TB 8
#define TT 400
#define TS 40
#define TV 512
#define SU (TS + 1)          // 41
#define NROWS (TB * TT * SU) // 131200
#define KCH 16               // t-steps per register chunk
#define NCH (TT / KCH)       // 25 chunks
#define NEG_INF (-1.0e30f)
#define INV_LN2 1.44269504088896341f
#define LN2 0.69314718055994531f

__global__ __launch_bounds__(256) void rowlse_kernel(
    const float* __restrict__ acts, const int* __restrict__ labels,
    float* __restrict__ lp_blank, float* __restrict__ lp_label)
{
    const int wave = threadIdx.x >> 6;
    const int lane = threadIdx.x & 63;
    const int row  = blockIdx.x * 4 + wave;   // grid*4 == NROWS exactly

    const float* rp = acts + (size_t)row * TV;
    // lane i covers elements [8i, 8i+8)
    float4 a = *(const float4*)(rp + lane * 8);
    float4 b = *(const float4*)(rp + lane * 8 + 4);

    float m = fmaxf(fmaxf(fmaxf(a.x, a.y), fmaxf(a.z, a.w)),
                    fmaxf(fmaxf(b.x, b.y), fmaxf(b.z, b.w)));
#pragma unroll
    for (int off = 1; off < 64; off <<= 1) m = fmaxf(m, __shfl_xor(m, off));

    float s = __expf(a.x - m) + __expf(a.y - m) + __expf(a.z - m) + __expf(a.w - m)
            + __expf(b.x - m) + __expf(b.y - m) + __expf(b.z - m) + __expf(b.w - m);
#pragma unroll
    for (int off = 1; off < 64; off <<= 1) s += __shfl_xor(s, off);

    const float logZ = m + logf(s);

    if (lane == 0) {
        const int u  = row % SU;
        const int bt = row / SU;
        // store in log2 domain (recursion runs base-2: v_exp/v_log are native base-2)
        lp_blank[row] = (a.x - logZ) * INV_LN2;
        if (u < TS) {
            const int b_idx = bt / TT;
            const int col   = labels[b_idx * TS + u];
            lp_label[bt * TS + u] = (rp[col] - logZ) * INV_LN2;   // L1-hot reload
        }
    }
}

// VALU whole-wave shift-up-by-1 (DPP wave_shr:1) — replaces ds_bpermute-based
// __shfl_up (~40cy DS latency) with ~4-8cy VALU latency on the serial chain.
// bound_ctrl=true: lane 0 sources 0; harmless, lane 0's move term is -1e30.
__device__ __forceinline__ float wave_shr1(float x) {
    return __int_as_float(
        __builtin_amdgcn_update_dpp(0, __float_as_int(x), 0x138, 0xf, 0xf, true));
}

// One wave per batch. Lane u holds alpha[u] (log2 domain). t-loop software-
// pipelined: 16-step chunks double-buffered in registers (A/B, outer loop
// unrolled x2 so all buffer indices are compile-time constants).
__global__ __launch_bounds__(64) void alpha_kernel(
    const float* __restrict__ lp_blank, const float* __restrict__ lp_label,
    const int* __restrict__ input_lengths, const int* __restrict__ label_lengths,
    float* __restrict__ out)
{
    const int b = blockIdx.x;
    const int u = threadIdx.x;          // one wave: u in [0,64)

    const int inlen  = input_lengths[b];
    const int lablen = label_lengths[b];

    // clamped addresses so dead lanes (u>TS) read valid memory
    const int uu = (u <= TS) ? u : TS;
    const int ul = (u >= 1 && u <= TS) ? (u - 1) : 0;
    const float* pb_ptr = lp_blank + (size_t)b * TT * SU + uu;
    const float* pl_ptr = lp_label + (size_t)b * TT * TS + ul;
    // lanes where the 'move' transition is invalid: poison lp_label at LOAD
    // time (off the serial critical path) -> logaddexp degenerates to 'stay'
    const bool u_dead = (u == 0 || u > TS);

    float alpha = (u == 0) ? 0.0f : NEG_INF;
    float saved = NEG_INF;

    float pbA[KCH], plA[KCH], pbB[KCH], plB[KCH];

#define LOADC(PB, PL, C) { \
    _Pragma("unroll") \
    for (int k = 0; k < KCH; ++k) { \
        (PB)[k] = pb_ptr[((C) * KCH + k) * SU]; \
        float plv = pl_ptr[((C) * KCH + k) * TS]; \
        (PL)[k] = u_dead ? NEG_INF : plv; \
    } }

#define COMPUTE(PB, PL, C) { \
    _Pragma("unroll") \
    for (int k = 0; k < KCH; ++k) { \
        const float prev = wave_shr1(alpha); \
        const float stay = alpha + (PB)[k]; \
        const float move = prev + (PL)[k]; \
        const float mx = fmaxf(stay, move); \
        const float mn = fminf(stay, move); \
        alpha = mx + __builtin_amdgcn_logf(1.0f + __builtin_amdgcn_exp2f(mn - mx)); \
        saved = ((C) * KCH + k == inlen - 1) ? alpha : saved; \
    } }

    LOADC(pbA, plA, 0);
    // 12 double-iterations cover chunks 0..23 and load up to chunk 24
    for (int i = 0; i < 12; ++i) {
        const int c0 = 2 * i;
        LOADC(pbB, plB, c0 + 1);
        COMPUTE(pbA, plA, c0);
        LOADC(pbA, plA, c0 + 2);
        COMPUTE(pbB, plB, c0 + 1);
    }
    COMPUTE(pbA, plA, NCH - 1);   // chunk 24

#undef LOADC
#undef COMPUTE

    const float cost_alpha = __shfl(saved, lablen);
    if (u == 0) out[b] = -cost_alpha * LN2;   // back to natural log
}

extern "C" void kernel_launch(void* const* d_in, const int* in_sizes, int n_in,
                              void* d_out, int out_size, void* d_ws, size_t ws_size,
                              hipStream_t stream) {
    const float* acts          = (const float*)d_in[0];
    const int*   labels        = (const int*)d_in[1];
    const int*   input_lengths = (const int*)d_in[2];
    const int*   label_lengths = (const int*)d_in[3];
    float* out = (float*)d_out;

    float* lp_blank = (float*)d_ws;                 // NROWS floats
    float* lp_label = lp_blank + NROWS;             // TB*TT*TS floats

    rowlse_kernel<<<NROWS / 4, 256, 0, stream>>>(acts, labels, lp_blank, lp_label);
    alpha_kernel<<<TB, 64, 0, stream>>>(lp_blank, lp_label,
                                        input_lengths, label_lengths, out);
}